// Round 7
// baseline (188.063 us; speedup 1.0000x reference)
//
#include <hip/hip_runtime.h>
#include <math.h>

// R7: revert R6 s_load weights (regressed 9us) back to LDS staging, but
// TRANSPOSED in LDS (swT[c][oc]) so the hot loop reads 2x/1x ds_read_b128
// instead of 8x/4x ds_read_b32 (LDS pipe was saturated in R5). ds-adder's
// 512 block-units load-balanced across front/bnpad/mid dispatches as riders.
// Fitted harness floor ~137us; optimizable kernel time ~35-44us.

#define HW 784      // 28*28
#define NB 4
#define STAGE 100

// ---------------- wave/block reduction helpers (wave64) --------------------
__device__ __forceinline__ float wredMax(float v){
  for (int o = 32; o > 0; o >>= 1) v = fmaxf(v, __shfl_down(v, o, 64));
  return v;
}
__device__ __forceinline__ float wredMin(float v){
  for (int o = 32; o > 0; o >>= 1) v = fminf(v, __shfl_down(v, o, 64));
  return v;
}
__device__ __forceinline__ double wredSumD(double v){
  for (int o = 32; o > 0; o >>= 1) v += __shfl_down(v, o, 64);
  return v;
}

__device__ float blockMin4(float v){
  __shared__ float shn[4];
  __syncthreads();
  v = wredMin(v);
  if ((threadIdx.x & 63) == 0) shn[threadIdx.x >> 6] = v;
  __syncthreads();
  return fminf(fminf(shn[0], shn[1]), fminf(shn[2], shn[3]));
}
__device__ float blockMax4(float v){
  __shared__ float shx[4];
  __syncthreads();
  v = wredMax(v);
  if ((threadIdx.x & 63) == 0) shx[threadIdx.x >> 6] = v;
  __syncthreads();
  return fmaxf(fmaxf(shx[0], shx[1]), fmaxf(shx[2], shx[3]));
}

// ---- per-block BN stats: 4 channels, sum+sumsq, double atomics (256 thr) --
__device__ void stats4(float v0, float v1, float v2, float v3,
                       double* sumP, double* sqP, int oc0){
  __shared__ double sred[4][8];
  __syncthreads();
  const int w = threadIdx.x >> 6;
  float vv[4] = {v0, v1, v2, v3};
  #pragma unroll
  for (int i = 0; i < 4; i++){
    double d = (double)vv[i];
    double s = wredSumD(d);
    double q = wredSumD(d * d);
    if ((threadIdx.x & 63) == 0){ sred[w][i] = s; sred[w][4 + i] = q; }
  }
  __syncthreads();
  if (threadIdx.x < 8){
    double tot = sred[0][threadIdx.x] + sred[1][threadIdx.x]
               + sred[2][threadIdx.x] + sred[3][threadIdx.x];
    int i = threadIdx.x & 3;
    if (threadIdx.x < 4) atomicAdd(&sumP[oc0 + i], tot);
    else                 atomicAdd(&sqP[oc0 + i],  tot);
  }
}
__device__ void stats2(float v0, float v1, double* sumP, double* sqP, int oc0){
  __shared__ double sred2[4][4];
  __syncthreads();
  const int w = threadIdx.x >> 6;
  float vv[2] = {v0, v1};
  #pragma unroll
  for (int i = 0; i < 2; i++){
    double d = (double)vv[i];
    double s = wredSumD(d);
    double q = wredSumD(d * d);
    if ((threadIdx.x & 63) == 0){ sred2[w][i] = s; sred2[w][2 + i] = q; }
  }
  __syncthreads();
  if (threadIdx.x < 4){
    double tot = sred2[0][threadIdx.x] + sred2[1][threadIdx.x]
               + sred2[2][threadIdx.x] + sred2[3][threadIdx.x];
    int i = threadIdx.x & 1;
    if (threadIdx.x < 2) atomicAdd(&sumP[oc0 + i], tot);
    else                 atomicAdd(&sqP[oc0 + i],  tot);
  }
}

// ---- KL partial accumulation: 4 sums -> 4 double atomics ------------------
__device__ void klAccum(float se, float sel, float sef, float sq, double* dst){
  __shared__ double kls[4][4];
  __syncthreads();
  const int w = threadIdx.x >> 6;
  double a0 = wredSumD((double)se);
  double a1 = wredSumD((double)sel);
  double a2 = wredSumD((double)sef);
  double a3 = wredSumD((double)sq);
  if ((threadIdx.x & 63) == 0){
    kls[w][0] = a0; kls[w][1] = a1; kls[w][2] = a2; kls[w][3] = a3;
  }
  __syncthreads();
  if (threadIdx.x < 4){
    double tot = kls[0][threadIdx.x] + kls[1][threadIdx.x]
               + kls[2][threadIdx.x] + kls[3][threadIdx.x];
    atomicAdd(&dst[threadIdx.x], tot);
  }
}

// ---- bin reconstruction (reference op order) ------------------------------
__device__ __forceinline__ float reconv(float vv, float mn, float rng,
                                        const float* saff){
  float q = (vv - mn) / rng * 100.0f;
  int idx = (int)floorf(q);
  float nv = 0.0f;
  if (idx < STAGE){
    int ci = idx < 0 ? 0 : (idx > STAGE - 1 ? STAGE - 1 : idx);
    nv = vv * saff[ci];
  }
  return nv;
}

// ---- reduce 16 per-block minmax partials ----------------------------------
__device__ __forceinline__ void mmReduce(const float* mmbuf, int tens,
                                         float& mn, float& mx){
  mn = 3.402823466e38f; mx = -3.402823466e38f;
  #pragma unroll
  for (int k = 0; k < 16; k++){
    mn = fminf(mn, mmbuf[tens * 32 + k]);
    mx = fmaxf(mx, mmbuf[tens * 32 + 16 + k]);
  }
}

// ---- ds-adder unit (u in [0,512)): 8 oc, 196-px chunk, transposed LDS -----
// dstat: [0:256) ds_sum [256:512) ds_sq ... [1280:1296) kl slots
__device__ void dsUnit(int u, const float* __restrict__ x,
                       const float* __restrict__ w_ds,
                       const float* __restrict__ a_ds,
                       const float* __restrict__ lap_ds,
                       const float* __restrict__ mmbuf,
                       float* __restrict__ A, double* __restrict__ dS)
{
  const int t = threadIdx.x;
  const int chunk = u & 3, og = (u >> 2) & 31, b = u >> 7;
  const int oc0 = og * 8;
  __shared__ float saff[STAGE];
  __shared__ float swT[1024];            // [c][8 oc] transposed
  if (t < STAGE) saff[t] = a_ds[t];
  float mn, mx; mmReduce(mmbuf, 0, mn, mx);
  const float rng = mx - mn;
  __syncthreads();
  for (int k = t; k < 1024; k += 256){
    int loc = k >> 7, c = k & 127;
    swT[c * 8 + loc] = reconv(w_ds[(oc0 + loc) * 128 + c], mn, rng, saff);
  }
  __syncthreads();
  const float4* swT4 = (const float4*)swT;

  const int px = chunk * 196 + t;
  float v0=0,v1=0,v2=0,v3=0,v4=0,v5=0,v6=0,v7=0;
  if (t < 196){
    const float* xp = x + (size_t)b * 128 * HW + px;
    float c0=0,c1=0,c2=0,c3=0,c4=0,c5=0,c6=0,c7=0;
    #pragma unroll 4
    for (int c = 0; c < 128; c++){
      float xv = xp[(size_t)c * HW];
      float4 wa = swT4[c * 2];
      float4 wb = swT4[c * 2 + 1];
      c0 += fabsf(xv - wa.x); c1 += fabsf(xv - wa.y);
      c2 += fabsf(xv - wa.z); c3 += fabsf(xv - wa.w);
      c4 += fabsf(xv - wb.x); c5 += fabsf(xv - wb.y);
      c6 += fabsf(xv - wb.z); c7 += fabsf(xv - wb.w);
    }
    v0=-c0; v1=-c1; v2=-c2; v3=-c3; v4=-c4; v5=-c5; v6=-c6; v7=-c7;
    float* op = A + ((size_t)(b * 256 + oc0)) * HW + px;
    op[0]=v0; op[HW]=v1; op[2*HW]=v2; op[3*HW]=v3;
    op[4*HW]=v4; op[5*HW]=v5; op[6*HW]=v6; op[7*HW]=v7;
  }
  stats4(v0, v1, v2, v3, dS + 0, dS + 256, oc0);
  stats4(v4, v5, v6, v7, dS + 0, dS + 256, oc0 + 4);

  if ((u & 3) == 0 && (u >> 7) == 0){    // chunk==0, b==0: KL rider (32 units)
    float se = 0, sel = 0, sef = 0, sq = 0;
    for (int k = t; k < 1024; k += 256){
      int loc = k >> 7, c = k & 127;
      float f = swT[c * 8 + loc];
      float l = lap_ds[(oc0 + loc) * 128 + c];
      float e = expf(l);
      se += e; sel += e * l; sef += e * f; sq += expf(f);
    }
    klAccum(se, sel, sef, sq, dS + 1280 + 0);
  }
}

// --------------- K0: partial min/max (64 blocks) + zero dstat --------------
__global__ __launch_bounds__(256) void minmax_kernel(
    const float* w0, int n0, const float* w1, int n1,
    const float* w2, int n2, const float* w3, int n3,
    float* mmbuf, double* dstat)
{
  if (threadIdx.x < 21) dstat[blockIdx.x * 21 + threadIdx.x] = 0.0;
  const int tens = blockIdx.x >> 4, slot = blockIdx.x & 15;
  const float* w; int n;
  if      (tens == 0){ w = w0; n = n0; }
  else if (tens == 1){ w = w1; n = n1; }
  else if (tens == 2){ w = w2; n = n2; }
  else               { w = w3; n = n3; }
  float mn = 3.402823466e38f, mx = -3.402823466e38f;
  for (int i = slot * 256 + threadIdx.x; i < n; i += 4096){
    float v = w[i];
    mn = fminf(mn, v); mx = fmaxf(mx, v);
  }
  mn = blockMin4(mn); mx = blockMax4(mx);
  if (threadIdx.x == 0){
    mmbuf[tens * 32 + slot]      = mn;
    mmbuf[tens * 32 + 16 + slot] = mx;
  }
}

// --------------- K1: front — c1+PEG [0,256) + ds [256,384) + riders --------
// [384,448): recon+write f_c2 row + KL(t2);  [448,464): KL(t3)
__global__ __launch_bounds__(256) void front_kernel(
    const float* __restrict__ x,
    const float* __restrict__ w_ds, const float* __restrict__ a_ds,
    const float* __restrict__ lap_ds,
    const float* __restrict__ w_c1, const float* __restrict__ a_c1,
    const float* __restrict__ lap_c1,
    const float* __restrict__ w_c2, const float* __restrict__ a_c2,
    const float* __restrict__ lap_c2, float* __restrict__ f_c2,
    const float* __restrict__ w_c3, const float* __restrict__ a_c3,
    const float* __restrict__ lap_c3,
    const float* __restrict__ peg_w, const float* __restrict__ mmbuf,
    float* __restrict__ A, float* __restrict__ T2, double* __restrict__ dS)
{
  const int t = threadIdx.x;
  if (blockIdx.x < 256){
    // ---------------- adder_c1 + PEG ----------------
    const int a = blockIdx.x;
    const int rc = a & 3, og = (a >> 2) & 15, b = a >> 6;
    const int oc0 = og * 4;
    __shared__ float saffc[STAGE];
    __shared__ float swcT[512];          // [c][4 oc]
    __shared__ float swp[36];
    __shared__ float sT1[4][256];
    if (t < STAGE) saffc[t] = a_c1[t];
    if (t >= 128 && t < 164) swp[t - 128] = peg_w[oc0 * 9 + (t - 128)];
    float mn, mx; mmReduce(mmbuf, 1, mn, mx);
    const float rng = mx - mn;
    __syncthreads();
    for (int k = t; k < 512; k += 256){
      int loc = k >> 7, c = k & 127;
      swcT[c * 4 + loc] = reconv(w_c1[(oc0 + loc) * 128 + c], mn, rng, saffc);
    }
    __syncthreads();
    const float4* swcT4 = (const float4*)swcT;

    if (t < 252){
      const int rr = t / 28;
      const int col = t - rr * 28;
      const int wr = rc * 7 - 1 + rr;
      float tv0 = 0, tv1 = 0, tv2 = 0, tv3 = 0;
      if (wr >= 0 && wr < 28){
        const float* xp = x + (size_t)b * 128 * HW + wr * 28 + col;
        float c0 = 0, c1 = 0, c2 = 0, c3 = 0;
        #pragma unroll 4
        for (int c = 0; c < 128; c++){
          float xv = xp[(size_t)c * HW];
          float4 wv = swcT4[c];
          c0 += fabsf(xv - wv.x);
          c1 += fabsf(xv - wv.y);
          c2 += fabsf(xv - wv.z);
          c3 += fabsf(xv - wv.w);
        }
        tv0 = -c0; tv1 = -c1; tv2 = -c2; tv3 = -c3;
      }
      sT1[0][t] = tv0; sT1[1][t] = tv1; sT1[2][t] = tv2; sT1[3][t] = tv3;
    }
    __syncthreads();
    float v0 = 0, v1 = 0, v2 = 0, v3 = 0;
    if (t < 196){
      const int r = t / 28, col = t - r * 28;
      float c0 = 0, c1 = 0, c2 = 0, c3 = 0;
      #pragma unroll
      for (int ky = 0; ky < 3; ky++){
        #pragma unroll
        for (int kx = 0; kx < 3; kx++){
          int cc = col + kx - 1;
          bool ok = (cc >= 0) && (cc < 28);
          int idx = ok ? ((r + ky) * 28 + cc) : 0;
          float p0 = ok ? sT1[0][idx] : 0.0f;
          float p1 = ok ? sT1[1][idx] : 0.0f;
          float p2 = ok ? sT1[2][idx] : 0.0f;
          float p3 = ok ? sT1[3][idx] : 0.0f;
          int wk = ky * 3 + kx;
          c0 += fabsf(p0 - swp[wk]);
          c1 += fabsf(p1 - swp[9 + wk]);
          c2 += fabsf(p2 - swp[18 + wk]);
          c3 += fabsf(p3 - swp[27 + wk]);
        }
      }
      v0 = -c0; v1 = -c1; v2 = -c2; v3 = -c3;
      const int opx = (rc * 7 + r) * 28 + col;
      float* op = T2 + ((size_t)(b * 64 + oc0)) * HW + opx;
      op[0] = v0; op[HW] = v1; op[2 * HW] = v2; op[3 * HW] = v3;
    }
    stats4(v0, v1, v2, v3, dS + 512, dS + 576, oc0);

    if (b == 0 && rc == 0){              // KL rider for tensor 1 (16 units)
      float se = 0, sel = 0, sef = 0, sq = 0;
      for (int k = t; k < 512; k += 256){
        int loc = k >> 7, c = k & 127;
        float f = swcT[c * 4 + loc];
        float l = lap_c1[(oc0 + loc) * 128 + c];
        float e = expf(l);
        se += e; sel += e * l; sef += e * f; sq += expf(f);
      }
      klAccum(se, sel, sef, sq, dS + 1280 + 4);
    }
  } else if (blockIdx.x < 384){
    dsUnit(blockIdx.x - 256, x, w_ds, a_ds, lap_ds, mmbuf, A, dS);
  } else if (blockIdx.x < 448){
    // ---------------- f_c2 writer + KL (tensor 2) ----------------
    const int j = blockIdx.x - 384;      // oc row 0..63, 576 elems
    __shared__ float saff2[STAGE];
    if (t < STAGE) saff2[t] = a_c2[t];
    float mn, mx; mmReduce(mmbuf, 2, mn, mx);
    const float rng = mx - mn;
    __syncthreads();
    float se = 0, sel = 0, sef = 0, sq = 0;
    for (int k = t; k < 576; k += 256){
      float nv = reconv(w_c2[j * 576 + k], mn, rng, saff2);
      f_c2[j * 576 + k] = nv;
      float l = lap_c2[j * 576 + k];
      float e = expf(l);
      se += e; sel += e * l; sef += e * nv; sq += expf(nv);
    }
    klAccum(se, sel, sef, sq, dS + 1280 + 8);
  } else {
    // ---------------- KL (tensor 3) ----------------
    const int j = blockIdx.x - 448;      // slice of 1024
    __shared__ float saff3[STAGE];
    if (t < STAGE) saff3[t] = a_c3[t];
    float mn, mx; mmReduce(mmbuf, 3, mn, mx);
    const float rng = mx - mn;
    __syncthreads();
    float se = 0, sel = 0, sef = 0, sq = 0;
    for (int k = t; k < 1024; k += 256){
      float nv = reconv(w_c3[j * 1024 + k], mn, rng, saff3);
      float l = lap_c3[j * 1024 + k];
      float e = expf(l);
      se += e; sel += e * l; sef += e * nv; sq += expf(nv);
    }
    klAccum(se, sel, sef, sq, dS + 1280 + 12);
  }
}

// --------------- K2: bnpad [0,256) + ds riders [256,448) -------------------
__global__ __launch_bounds__(256) void bnpad_kernel(
    const float* __restrict__ T2, float* __restrict__ T2b,
    const float* __restrict__ g1, const float* __restrict__ b1,
    const float* __restrict__ x, const float* __restrict__ w_ds,
    const float* __restrict__ a_ds, const float* __restrict__ lap_ds,
    const float* __restrict__ mmbuf, float* __restrict__ A,
    double* __restrict__ dS)
{
  if (blockIdx.x < 256){
    const int a = blockIdx.x;           // b*64 + c
    const int c = a & 63;
    __shared__ float ssc, ssb;
    if (threadIdx.x == 0){
      double s  = dS[512 + c] * (1.0 / 3136.0);
      double vr = dS[576 + c] * (1.0 / 3136.0) - s * s;
      float scale = g1[c] * rsqrtf((float)vr + 1e-5f);
      ssc = scale; ssb = b1[c] - (float)s * scale;
    }
    __syncthreads();
    const float sc_ = ssc, bi_ = ssb;
    const float* src = T2 + (size_t)a * HW;
    float* dst = T2b + (size_t)a * 960;
    for (int i = threadIdx.x; i < 960; i += 256){
      int row = i >> 5, col = i & 31;
      float v = 0.0f;
      if (row >= 1 && row <= 28 && col >= 1 && col <= 28)
        v = fmaxf(src[(row - 1) * 28 + (col - 1)] * sc_ + bi_, 0.0f);
      dst[i] = v;
    }
  } else {
    dsUnit(128 + (blockIdx.x - 256), x, w_ds, a_ds, lap_ds, mmbuf, A, dS);
  }
}

// --------------- K3: mid3x3 [0,512) + ds riders [512,704) ------------------
__global__ __launch_bounds__(256) void mid3x3_kernel(
    const float* __restrict__ T2b, const float* __restrict__ f_c2,
    float* __restrict__ T3,
    const float* __restrict__ x, const float* __restrict__ w_ds,
    const float* __restrict__ a_ds, const float* __restrict__ lap_ds,
    const float* __restrict__ mmbuf, float* __restrict__ A,
    double* __restrict__ dS)
{
  if (blockIdx.x < 512){
    const int t = threadIdx.x;
    const int a = blockIdx.x;
    const int chunk = a & 3, og = (a >> 2) & 31, b = a >> 7;
    const int oc0 = og * 2;
    const float* __restrict__ wA = f_c2 + oc0 * 576;
    const float* __restrict__ wB = wA + 576;

    float v0 = 0, v1 = 0;
    const int px = chunk * 196 + t;
    if (t < 196){
      const int y = px / 28, xc = px - y * 28;
      const float* base = T2b + (size_t)b * 64 * 960 + y * 32 + xc;
      float c0 = 0, c1 = 0;
      #pragma unroll 2
      for (int c = 0; c < 64; c++){
        const float* p = base + c * 960;
        float t0 = p[0],  t1 = p[1],  t2 = p[2];
        float t3 = p[32], t4 = p[33], t5 = p[34];
        float t6 = p[64], t7 = p[65], t8 = p[66];
        const float* wa = wA + c * 9;
        const float* wb = wB + c * 9;
        c0 += fabsf(t0 - wa[0]) + fabsf(t1 - wa[1]) + fabsf(t2 - wa[2])
            + fabsf(t3 - wa[3]) + fabsf(t4 - wa[4]) + fabsf(t5 - wa[5])
            + fabsf(t6 - wa[6]) + fabsf(t7 - wa[7]) + fabsf(t8 - wa[8]);
        c1 += fabsf(t0 - wb[0]) + fabsf(t1 - wb[1]) + fabsf(t2 - wb[2])
            + fabsf(t3 - wb[3]) + fabsf(t4 - wb[4]) + fabsf(t5 - wb[5])
            + fabsf(t6 - wb[6]) + fabsf(t7 - wb[7]) + fabsf(t8 - wb[8]);
      }
      v0 = -c0; v1 = -c1;
      T3[((size_t)(b * 64 + oc0)) * HW + px]     = v0;
      T3[((size_t)(b * 64 + oc0 + 1)) * HW + px] = v1;
    }
    stats2(v0, v1, dS + 640, dS + 704, oc0);
  } else {
    dsUnit(320 + (blockIdx.x - 512), x, w_ds, a_ds, lap_ds, mmbuf, A, dS);
  }
}

// --------------- K4: adder 1x1 64->256 (bn2 inline, transposed LDS) --------
__global__ __launch_bounds__(256) void back_kernel(
    const float* __restrict__ T3, const float* __restrict__ w_c3,
    const float* __restrict__ a_c3, const float* __restrict__ mmbuf,
    const float* __restrict__ g2, const float* __restrict__ b2,
    float* __restrict__ out, double* __restrict__ dS)
{
  const int t = threadIdx.x;
  const int a = blockIdx.x;
  const int chunk = a & 3, og = (a >> 2) & 63, b = a >> 8;
  const int oc0 = og * 4;
  __shared__ float ssc[64], ssb[64], swbT[256], saff[STAGE];
  if (t < 64){
    double s  = dS[640 + t] * (1.0 / 3136.0);
    double vr = dS[704 + t] * (1.0 / 3136.0) - s * s;
    float scale = g2[t] * rsqrtf((float)vr + 1e-5f);
    ssc[t] = scale; ssb[t] = b2[t] - (float)s * scale;
  }
  if (t >= 128 && t < 128 + STAGE) saff[t - 128] = a_c3[t - 128];
  float mn, mx; mmReduce(mmbuf, 3, mn, mx);
  const float rng = mx - mn;
  __syncthreads();
  {
    int loc = t >> 6, c = t & 63;
    swbT[c * 4 + loc] = reconv(w_c3[(oc0 + loc) * 64 + c], mn, rng, saff);
  }
  __syncthreads();
  const float4* swbT4 = (const float4*)swbT;

  const int px = chunk * 196 + t;
  float v0 = 0, v1 = 0, v2 = 0, v3 = 0;
  if (t < 196){
    const float* bp = T3 + (size_t)b * 64 * HW + px;
    float c0 = 0, c1 = 0, c2 = 0, c3 = 0;
    #pragma unroll 4
    for (int c = 0; c < 64; c++){
      float raw = bp[(size_t)c * HW];
      float vv = fmaxf(raw * ssc[c] + ssb[c], 0.0f);
      float4 wv = swbT4[c];
      c0 += fabsf(vv - wv.x);
      c1 += fabsf(vv - wv.y);
      c2 += fabsf(vv - wv.z);
      c3 += fabsf(vv - wv.w);
    }
    v0 = -c0; v1 = -c1; v2 = -c2; v3 = -c3;
    float* op = out + ((size_t)(b * 256 + oc0)) * HW + px;
    op[0] = v0; op[HW] = v1; op[2 * HW] = v2; op[3 * HW] = v3;
  }
  stats4(v0, v1, v2, v3, dS + 768, dS + 1024, oc0);
}

// --------------- K5: bn3 + bnds finalize, residual, relu, kl ---------------
__global__ __launch_bounds__(256) void final_kernel(
    float* __restrict__ out, const float* __restrict__ A,
    const float* __restrict__ g3, const float* __restrict__ b3,
    const float* __restrict__ gds, const float* __restrict__ bds,
    const double* __restrict__ dS)
{
  __shared__ float s3c[256], s3b[256], sdc[256], sdb[256];
  const int t = threadIdx.x;
  {
    double s  = dS[768 + t] * (1.0 / 3136.0);
    double vr = dS[1024 + t] * (1.0 / 3136.0) - s * s;
    float scale = g3[t] * rsqrtf((float)vr + 1e-5f);
    s3c[t] = scale; s3b[t] = b3[t] - (float)s * scale;
    s  = dS[t] * (1.0 / 3136.0);
    vr = dS[256 + t] * (1.0 / 3136.0) - s * s;
    scale = gds[t] * rsqrtf((float)vr + 1e-5f);
    sdc[t] = scale; sdb[t] = bds[t] - (float)s * scale;
  }
  __syncthreads();
  #pragma unroll
  for (int k = 0; k < 4; k++){
    int n = blockIdx.x * 1024 + k * 256 + t;
    int c = (n / HW) & 255;
    float h = out[n], aa = A[n];
    float r = fmaxf(aa * sdc[c] + sdb[c], 0.0f);
    out[n] = fmaxf(h * s3c[c] + s3b[c] + r, 0.0f);
  }
  if (blockIdx.x == 0 && t == 0){
    const int ns[4] = {32768, 8192, 36864, 16384};
    float kl = 0.0f;
    #pragma unroll
    for (int q = 0; q < 4; q++){
      double se  = dS[1280 + q * 4];
      double sel = dS[1280 + q * 4 + 1];
      double sef = dS[1280 + q * 4 + 2];
      double sq  = dS[1280 + q * 4 + 3];
      kl += (float)((((sel - sef) / se) - log(se) + log(sq)) / (double)ns[q]);
    }
    out[802816] = kl;
  }
}

// ===========================================================================
extern "C" void kernel_launch(void* const* d_in, const int* in_sizes, int n_in,
                              void* d_out, int out_size, void* d_ws, size_t ws_size,
                              hipStream_t stream)
{
  const float* x      = (const float*)d_in[0];
  const float* sw_ds  = (const float*)d_in[1];
  const float* sw_c1  = (const float*)d_in[2];
  const float* sw_c2  = (const float*)d_in[3];
  const float* sw_c3  = (const float*)d_in[4];
  const float* a_ds   = (const float*)d_in[5];
  const float* a_c1   = (const float*)d_in[6];
  const float* a_c2   = (const float*)d_in[7];
  const float* a_c3   = (const float*)d_in[8];
  const float* peg_w  = (const float*)d_in[9];
  const float* bn1_g  = (const float*)d_in[10];
  const float* bn1_b  = (const float*)d_in[11];
  const float* bn2_g  = (const float*)d_in[12];
  const float* bn2_b  = (const float*)d_in[13];
  const float* bn3_g  = (const float*)d_in[14];
  const float* bn3_b  = (const float*)d_in[15];
  const float* bnds_g = (const float*)d_in[16];
  const float* bnds_b = (const float*)d_in[17];
  const float* lap_ds = (const float*)d_in[18];
  const float* lap_c1 = (const float*)d_in[19];
  const float* lap_c2 = (const float*)d_in[20];
  const float* lap_c3 = (const float*)d_in[21];

  float* ws    = (float*)d_ws;
  float* f_c2  = ws;                        // 36864
  float* mmbuf = ws + 36864;                // 128
  double* dstat= (double*)(ws + 36992);     // 1344 doubles = 2688 floats
  float* A     = ws + 39680;                // 802816
  float* T2    = ws + 842496;               // 200704
  float* T3    = ws + 1043200;              // 200704
  float* T2b   = ws + 1243904;              // 245760

  float* out = (float*)d_out;

  minmax_kernel<<<64, 256, 0, stream>>>(
      sw_ds, 32768, sw_c1, 8192, sw_c2, 36864, sw_c3, 16384, mmbuf, dstat);

  front_kernel<<<464, 256, 0, stream>>>(
      x, sw_ds, a_ds, lap_ds, sw_c1, a_c1, lap_c1,
      sw_c2, a_c2, lap_c2, f_c2, sw_c3, a_c3, lap_c3,
      peg_w, mmbuf, A, T2, dstat);

  bnpad_kernel<<<448, 256, 0, stream>>>(T2, T2b, bn1_g, bn1_b,
                                        x, sw_ds, a_ds, lap_ds, mmbuf, A, dstat);

  mid3x3_kernel<<<704, 256, 0, stream>>>(T2b, f_c2, T3,
                                         x, sw_ds, a_ds, lap_ds, mmbuf, A, dstat);

  back_kernel<<<1024, 256, 0, stream>>>(T3, sw_c3, a_c3, mmbuf,
                                        bn2_g, bn2_b, out, dstat);

  final_kernel<<<784, 256, 0, stream>>>(out, A, bn3_g, bn3_b, bnds_g, bnds_b,
                                        dstat);
}